// Round 6
// baseline (4509.924 us; speedup 1.0000x reference)
//
#include <hip/hip_runtime.h>
#include <hip/hip_bf16.h>
#include <hip/hip_cooperative_groups.h>

namespace cg = cooperative_groups;

#define BATCH 64
#define NPIX 196
#define ENCD 2048
#define ATTD 512
#define DECD 512
#define EMBD 512
#define NVOCAB 10000
#define TSTEPS 24
#define KX 3072
#define NPAD 10112

typedef short bf16x8 __attribute__((ext_vector_type(8)));
typedef float f32x4 __attribute__((ext_vector_type(4)));

__device__ inline ushort f2bf(float f) {
    union { float f; unsigned u; } v; v.f = f;
    unsigned r = (v.u + 0x7fff + ((v.u >> 16) & 1)) >> 16;
    return (ushort)r;
}
__device__ inline float bf2f(ushort u) {
    union { unsigned u; float f; } v; v.u = ((unsigned)u) << 16;
    return v.f;
}

// ---------------- WTj[j][k] bf16 + meta fused ----------------
__global__ __launch_bounds__(256) void k_cp_wtj(const float* __restrict__ Wih,
                                                const float* __restrict__ Whh,
                                                const int* __restrict__ caps,
                                                const int* __restrict__ lens,
                                                ushort* __restrict__ WTj,
                                                float* __restrict__ cap_out,
                                                float* __restrict__ len_out) {
    int j = blockIdx.x;
    for (int k = threadIdx.x; k < KX; k += 256) {
        float v = (k < 2560) ? Wih[(size_t)j * 2560 + k] : Whh[(size_t)j * 512 + (k - 2560)];
        WTj[(size_t)j * KX + k] = f2bf(v);
    }
    if (blockIdx.x == 0) {
        for (int i = threadIdx.x; i < 1664; i += 256) {
            if (i < 1600) cap_out[i] = (float)caps[i];
            else          len_out[i - 1600] = (float)(lens[i - 1600] - 1);
        }
    }
}

// ---------------- transposes to [n][k] bf16 ----------------
__global__ __launch_bounds__(256) void k_tr_bpre(const float* __restrict__ Wd,
                                                 const float* __restrict__ Wfb,
                                                 ushort* __restrict__ out) {
    __shared__ float tile[32][33];
    int nb = blockIdx.x * 32, kb = blockIdx.y * 32;
    int tx = threadIdx.x & 31, ty = threadIdx.x >> 5;
    for (int i = 0; i < 32; i += 8) {
        int k = kb + ty + i, n = nb + tx;
        float v = (n < ATTD) ? Wd[(size_t)k * ATTD + n] : Wfb[(size_t)k * ENCD + (n - ATTD)];
        tile[ty + i][tx] = v;
    }
    __syncthreads();
    for (int i = 0; i < 32; i += 8)
        out[(size_t)(nb + ty + i) * 512 + kb + tx] = f2bf(tile[tx][ty + i]);
}

__global__ __launch_bounds__(256) void k_tr_wfct(const float* __restrict__ Wfc,
                                                 ushort* __restrict__ out) {
    __shared__ float tile[32][33];
    int nb = blockIdx.x * 32, kb = blockIdx.y * 32;
    int tx = threadIdx.x & 31, ty = threadIdx.x >> 5;
    for (int i = 0; i < 32; i += 8) {
        int k = kb + ty + i, n = nb + tx;
        float v = (n < NVOCAB) ? Wfc[(size_t)k * NVOCAB + n] : 0.f;
        tile[ty + i][tx] = v;
    }
    __syncthreads();
    for (int i = 0; i < 32; i += 8)
        out[(size_t)(nb + ty + i) * 512 + kb + tx] = f2bf(tile[tx][ty + i]);
}

__global__ __launch_bounds__(256) void k_tr_wet(const float* __restrict__ We,
                                                ushort* __restrict__ out) {
    __shared__ float tile[32][33];
    int nb = blockIdx.x * 32, kb = blockIdx.y * 32;
    int tx = threadIdx.x & 31, ty = threadIdx.x >> 5;
    for (int i = 0; i < 32; i += 8) {
        int k = kb + ty + i, n = nb + tx;
        tile[ty + i][tx] = We[(size_t)k * ATTD + n];
    }
    __syncthreads();
    for (int i = 0; i < 32; i += 8)
        out[(size_t)(nb + ty + i) * ENCD + kb + tx] = f2bf(tile[tx][ty + i]);
}

// ---------------- embpart (bf16) = gathered emb @ WTj[:, :512]^T ----------------
__global__ __launch_bounds__(256) void k_embpart(const int* __restrict__ caps,
                                                 const float* __restrict__ emb,
                                                 const ushort* __restrict__ WTj,
                                                 ushort* __restrict__ embpartb) {
    int w = threadIdx.x >> 6, l = threadIdx.x & 63;
    int m = l & 15, kg = l >> 4;
    int r0 = blockIdx.x * 64;
    int n = blockIdx.y * 64 + w * 16 + m;
    const ushort* B = WTj + (size_t)n * KX + kg * 8;
    int tok[4];
#pragma unroll
    for (int mf = 0; mf < 4; ++mf) {
        int row = r0 + m + mf * 16;
        tok[mf] = caps[(row & 63) * 25 + (row >> 6)];
    }
    f32x4 acc[4] = {};
#pragma unroll 4
    for (int k0 = 0; k0 < 512; k0 += 32) {
        bf16x8 bfr = *(const bf16x8*)(B + k0);
#pragma unroll
        for (int mf = 0; mf < 4; ++mf) {
            const float* ap = emb + (size_t)tok[mf] * 512 + kg * 8 + k0;
            float4 f0 = *(const float4*)ap;
            float4 f1 = *(const float4*)(ap + 4);
            bf16x8 a;
            a[0] = f2bf(f0.x); a[1] = f2bf(f0.y); a[2] = f2bf(f0.z); a[3] = f2bf(f0.w);
            a[4] = f2bf(f1.x); a[5] = f2bf(f1.y); a[6] = f2bf(f1.z); a[7] = f2bf(f1.w);
            acc[mf] = __builtin_amdgcn_mfma_f32_16x16x32_bf16(a, bfr, acc[mf], 0, 0, 0);
        }
    }
#pragma unroll
    for (int mf = 0; mf < 4; ++mf)
#pragma unroll
        for (int r = 0; r < 4; ++r)
            embpartb[(size_t)(r0 + mf * 16 + kg * 4 + r) * 2048 + n] = f2bf(acc[mf][r]);
}

// ---------------- enc fp32 -> bf16 ----------------
__global__ void k_encconv(const float* __restrict__ enc, ushort* __restrict__ encb) {
    size_t i = ((size_t)blockIdx.x * 256 + threadIdx.x) * 8;
    float4 f0 = *(const float4*)(enc + i);
    float4 f1 = *(const float4*)(enc + i + 4);
    union { bf16x8 v; ushort u[8]; } o;
    o.u[0] = f2bf(f0.x); o.u[1] = f2bf(f0.y); o.u[2] = f2bf(f0.z); o.u[3] = f2bf(f0.w);
    o.u[4] = f2bf(f1.x); o.u[5] = f2bf(f1.y); o.u[6] = f2bf(f1.z); o.u[7] = f2bf(f1.w);
    *(bf16x8*)(encb + i) = o.v;
}

// ---------------- mean over 196 positions (bf16 in/out) ----------------
__global__ __launch_bounds__(256) void k_meanb(const ushort* __restrict__ encb,
                                               ushort* __restrict__ meanb) {
    int b = blockIdx.x, half = blockIdx.y;
    int e0 = half * 1024 + threadIdx.x * 4;
    const ushort* ep = encb + (size_t)b * NPIX * ENCD + e0;
    float s0 = 0.f, s1 = 0.f, s2 = 0.f, s3 = 0.f;
#pragma unroll 4
    for (int p = 0; p < NPIX; ++p) {
        ushort4 v = *(const ushort4*)(ep + (size_t)p * ENCD);
        s0 += bf2f(v.x); s1 += bf2f(v.y); s2 += bf2f(v.z); s3 += bf2f(v.w);
    }
    const float sc = 1.0f / NPIX;
    ushort4 o;
    o.x = f2bf(s0 * sc); o.y = f2bf(s1 * sc); o.z = f2bf(s2 * sc); o.w = f2bf(s3 * sc);
    *(ushort4*)(meanb + (size_t)b * ENCD + e0) = o;
}

// ---------------- h0/c0 init partials: K-split 8, atomic accumulate ----------------
__global__ __launch_bounds__(256) void k_initp(
        const ushort* __restrict__ meanb,
        const float* __restrict__ Wh, const float* __restrict__ Wc,
        float* __restrict__ hcacc) {
    __shared__ float mm[4][256];
    int bg = blockIdx.x * 4;
    int jy = blockIdx.y;
    int kz = blockIdx.z;
    int tid = threadIdx.x;
    for (int i = tid; i < 1024; i += 256) {
        int qq = i >> 8, k = i & 255;
        mm[qq][k] = bf2f(meanb[(size_t)(bg + qq) * ENCD + kz * 256 + k]);
    }
    __syncthreads();
    int j = jy * 256 + tid;
    const float* W; int col;
    if (j < 512) { W = Wh; col = j; } else { W = Wc; col = j - 512; }
    W += (size_t)(kz * 256) * 512 + col;
    float acc[4] = {};
    for (int k = 0; k < 256; ++k) {
        float w = W[(size_t)k * 512];
#pragma unroll
        for (int qq = 0; qq < 4; ++qq) acc[qq] += mm[qq][k] * w;
    }
#pragma unroll
    for (int qq = 0; qq < 4; ++qq)
        atomicAdd(hcacc + (size_t)(bg + qq) * 1024 + j, acc[qq]);
}

__global__ __launch_bounds__(256) void k_initfin(
        const float* __restrict__ hcacc, const float* __restrict__ bh,
        const float* __restrict__ bc, ushort* __restrict__ hbf,
        float* __restrict__ c) {
    int base = blockIdx.x * 2048;
    for (int i = threadIdx.x; i < 2048; i += 256) {
        int idx = base + i;
        int b = idx >> 10, n = idx & 1023;
        float v = hcacc[idx];
        if (n < 512) hbf[(size_t)b * 512 + n] = f2bf(v + bh[n]);
        else         c[(size_t)b * 512 + (n - 512)] = v + bc[n - 512];
    }
}

// ---------------- one-time: att1 = enc @ We + be (bf16 MFMA) ----------------
__global__ __launch_bounds__(256) void k_att1(
        const ushort* __restrict__ encb, const ushort* __restrict__ WeT,
        const float* __restrict__ be, ushort* __restrict__ att1b) {
    int w = threadIdx.x >> 6, l = threadIdx.x & 63;
    int wr = w >> 1, wc = w & 1;
    int m0 = blockIdx.x * 128 + wr * 64;
    int n0 = blockIdx.y * 128 + wc * 64;
    int ml = l & 15, kg = l >> 4;
    const ushort* aBase = encb + (size_t)(m0 + ml) * ENCD + kg * 8;
    const ushort* bBase = WeT + (size_t)(n0 + ml) * ENCD + kg * 8;
    f32x4 acc[4][4] = {};
    for (int k0 = 0; k0 < ENCD; k0 += 32) {
        bf16x8 bfr[4], afr[4];
#pragma unroll
        for (int nf = 0; nf < 4; ++nf)
            bfr[nf] = *(const bf16x8*)(bBase + (size_t)nf * 16 * ENCD + k0);
#pragma unroll
        for (int mf = 0; mf < 4; ++mf)
            afr[mf] = *(const bf16x8*)(aBase + (size_t)mf * 16 * ENCD + k0);
#pragma unroll
        for (int mf = 0; mf < 4; ++mf)
#pragma unroll
            for (int nf = 0; nf < 4; ++nf)
                acc[mf][nf] = __builtin_amdgcn_mfma_f32_16x16x32_bf16(afr[mf], bfr[nf], acc[mf][nf], 0, 0, 0);
    }
#pragma unroll
    for (int mf = 0; mf < 4; ++mf)
#pragma unroll
        for (int nf = 0; nf < 4; ++nf) {
            int col = n0 + nf * 16 + ml;
            float bias = be[col];
#pragma unroll
            for (int r = 0; r < 4; ++r) {
                int row = m0 + mf * 16 + kg * 4 + r;
                att1b[(size_t)row * ATTD + col] = f2bf(acc[mf][nf][r] + bias);
            }
        }
}

// ---------------- the cooperative loop: 2 grid.syncs per step ----------------
struct KP {
    const ushort* encb;
    const ushort* att1b;
    const ushort* WTj;
    const ushort* BpreT;
    const ushort* embpartb;
    const float* vatt;
    const float* bv;
    const float* bd;
    const float* bfb;
    const float* bih;
    const float* bhh;
    const int* lens;
    ushort* ctxb;
    ushort* hb0;
    ushort* hb1;
    float* c;
    ushort* hAll;
    float* alpha_out;
};

__global__ __launch_bounds__(512, 1) void k_loop(KP p) {
    cg::grid_group grid = cg::this_grid();
    __shared__ float h_lds[512];
    __shared__ float att2_lds[512];
    __shared__ float gate_lds[512];
    __shared__ float ev[200];
    __shared__ float inv_s;
    __shared__ float cpart[2][512];
    __shared__ float part[4][2][64][16];

    int blk = blockIdx.x, tid = threadIdx.x;
    int w = tid >> 6, l = tid & 63;
    int b = blk >> 2, q = blk & 3;

    // constants hoisted out of the t-loop
    float vvr[8];
#pragma unroll
    for (int i = 0; i < 8; ++i) vvr[i] = p.vatt[l * 8 + i];
    float bv0 = p.bv[0];
    float bd_t = p.bd[tid];
    float bfb_t = p.bfb[q * 512 + tid];
    const ushort* wrow_d = p.BpreT + (size_t)tid * 512;
    const ushort* wrow_f = p.BpreT + (size_t)(512 + q * 512 + tid) * 512;
    int lenb = p.lens[b] - 1;

    int m = l & 15, kg = l >> 4;
    int g = blk;
    int nt = w & 1, kh = w >> 1;

    for (int t = 0; t < TSTEPS; ++t) {
        const ushort* hcur = (t & 1) ? p.hb1 : p.hb0;
        ushort* hnxt = (t & 1) ? p.hb0 : p.hb1;

        // ---------- phase B: att2 + gate (redundant) + softmax + gated ctx ----------
        h_lds[tid] = bf2f(hcur[(size_t)b * 512 + tid]);
        __syncthreads();
        {
            float s = 0.f, sg = 0.f;
            for (int k0 = 0; k0 < 512; k0 += 8) {
                bf16x8 wv = *(const bf16x8*)(wrow_d + k0);
                bf16x8 gv = *(const bf16x8*)(wrow_f + k0);
#pragma unroll
                for (int i = 0; i < 8; ++i) {
                    float hk = h_lds[k0 + i];
                    s  += hk * bf2f((ushort)wv[i]);
                    sg += hk * bf2f((ushort)gv[i]);
                }
            }
            att2_lds[tid] = s + bd_t;
            gate_lds[tid] = 1.f / (1.f + __expf(-(sg + bfb_t)));
        }
        __syncthreads();
        {
            float a2r[8];
#pragma unroll
            for (int i = 0; i < 8; ++i) a2r[i] = att2_lds[l * 8 + i];
            for (int pp = w; pp < NPIX; pp += 8) {
                bf16x8 f = *(const bf16x8*)(p.att1b + ((size_t)b * NPIX + pp) * ATTD + l * 8);
                float s = 0.f;
#pragma unroll
                for (int i = 0; i < 8; ++i)
                    s += fmaxf(bf2f((ushort)f[i]) + a2r[i], 0.f) * vvr[i];
                for (int off = 32; off > 0; off >>= 1) s += __shfl_down(s, off);
                if (l == 0) ev[pp] = s + bv0;
            }
        }
        __syncthreads();
        if (w == 0) {
            float mx = -1e30f;
            for (int pp = l; pp < NPIX; pp += 64) mx = fmaxf(mx, ev[pp]);
            for (int off = 32; off > 0; off >>= 1) mx = fmaxf(mx, __shfl_down(mx, off));
            mx = __shfl(mx, 0);
            float s = 0.f;
            for (int pp = l; pp < NPIX; pp += 64) {
                float e_ = __expf(ev[pp] - mx);
                ev[pp] = e_;
                s += e_;
            }
            for (int off = 32; off > 0; off >>= 1) s += __shfl_down(s, off);
            if (l == 0) inv_s = 1.0f / s;
        }
        __syncthreads();
        float inv = inv_s;
        if (q == 0) {
            bool active = t < lenb;
            for (int pp = tid; pp < NPIX; pp += 512)
                p.alpha_out[((size_t)b * TSTEPS + t) * NPIX + pp] = active ? ev[pp] * inv : 0.f;
        }
        {
            int pg = tid >> 8, th = tid & 255;
            const ushort* ep = p.encb + (size_t)b * NPIX * ENCD + (size_t)pg * 98 * ENCD + q * 512 + th * 2;
            float s0 = 0.f, s1 = 0.f;
#pragma unroll 2
            for (int pp = 0; pp < 98; ++pp) {
                ushort2 v = *(const ushort2*)(ep + (size_t)pp * ENCD);
                float al = ev[pg * 98 + pp];
                s0 += al * bf2f(v.x);
                s1 += al * bf2f(v.y);
            }
            cpart[pg][th * 2]     = s0;
            cpart[pg][th * 2 + 1] = s1;
        }
        __syncthreads();
        if (tid < 256) {
            float s0 = (cpart[0][tid * 2]     + cpart[1][tid * 2])     * inv * gate_lds[tid * 2];
            float s1 = (cpart[0][tid * 2 + 1] + cpart[1][tid * 2 + 1]) * inv * gate_lds[tid * 2 + 1];
            ushort2 o; o.x = f2bf(s0); o.y = f2bf(s1);
            *(ushort2*)(p.ctxb + (size_t)b * 2048 + q * 512 + tid * 2) = o;
        }
        grid.sync();

        // ---------- phase C: gates GEMM (ctx K=2048 + h K=512) + LSTM ----------
        if (blk < 64) {
            int colsel = nt * 2 + (m >> 3);
            int jcol = colsel * 512 + g * 8 + (m & 7);
            const ushort* Brow = p.WTj + (size_t)jcol * KX;
            f32x4 acc[4] = {};
            const ushort* Bc = Brow + 512 + kh * 512 + kg * 8;
            const ushort* Ac = p.ctxb + (size_t)m * 2048 + kh * 512 + kg * 8;
#pragma unroll 4
            for (int k0 = 0; k0 < 512; k0 += 32) {
                bf16x8 bfr = *(const bf16x8*)(Bc + k0);
#pragma unroll
                for (int mf = 0; mf < 4; ++mf) {
                    bf16x8 afr = *(const bf16x8*)(Ac + (size_t)mf * 16 * 2048 + k0);
                    acc[mf] = __builtin_amdgcn_mfma_f32_16x16x32_bf16(afr, bfr, acc[mf], 0, 0, 0);
                }
            }
            const ushort* Bh = Brow + 2560 + kh * 128 + kg * 8;
            const ushort* Ah = hcur + (size_t)m * 512 + kh * 128 + kg * 8;
#pragma unroll
            for (int k0 = 0; k0 < 128; k0 += 32) {
                bf16x8 bfr = *(const bf16x8*)(Bh + k0);
#pragma unroll
                for (int mf = 0; mf < 4; ++mf) {
                    bf16x8 afr = *(const bf16x8*)(Ah + (size_t)mf * 16 * 512 + k0);
                    acc[mf] = __builtin_amdgcn_mfma_f32_16x16x32_bf16(afr, bfr, acc[mf], 0, 0, 0);
                }
            }
#pragma unroll
            for (int mf = 0; mf < 4; ++mf)
#pragma unroll
                for (int r = 0; r < 4; ++r)
                    part[kh][nt][mf * 16 + kg * 4 + r][m] = acc[mf][r];
            __syncthreads();
            {
                int bb = tid >> 3, dd = tid & 7;
                int d = g * 8 + dd;
                float gi = 0.f, gf = 0.f, gg = 0.f, go = 0.f;
#pragma unroll
                for (int k = 0; k < 4; ++k) {
                    gi += part[k][0][bb][dd];
                    gf += part[k][0][bb][8 + dd];
                    gg += part[k][1][bb][dd];
                    go += part[k][1][bb][8 + dd];
                }
                const ushort* eb = p.embpartb + ((size_t)t * 64 + bb) * 2048;
                gi += bf2f(eb[d])        + p.bih[d]        + p.bhh[d];
                gf += bf2f(eb[512 + d])  + p.bih[512 + d]  + p.bhh[512 + d];
                gg += bf2f(eb[1024 + d]) + p.bih[1024 + d] + p.bhh[1024 + d];
                go += bf2f(eb[1536 + d]) + p.bih[1536 + d] + p.bhh[1536 + d];
                ushort hout = hcur[(size_t)bb * 512 + d];
                if (t < p.lens[bb] - 1) {
                    float cc = p.c[(size_t)bb * 512 + d];
                    float si = 1.f / (1.f + __expf(-gi));
                    float sf = 1.f / (1.f + __expf(-gf));
                    float so = 1.f / (1.f + __expf(-go));
                    float cn = sf * cc + si * tanhf(gg);
                    float hn = so * tanhf(cn);
                    p.c[(size_t)bb * 512 + d] = cn;
                    hout = f2bf(hn);
                }
                hnxt[(size_t)bb * 512 + d] = hout;
                p.hAll[((size_t)t * 64 + bb) * 512 + d] = hout;
            }
        }
        grid.sync();
    }
}

// ---------------- post-loop: pred = hAll @ WfcT + bfc (masked) ----------------
__global__ __launch_bounds__(256) void k_predall(
        const ushort* __restrict__ hAll, const ushort* __restrict__ WfcT,
        const float* __restrict__ bfc, const int* __restrict__ lens,
        float* __restrict__ pred) {
    int w = threadIdx.x >> 6, l = threadIdx.x & 63;
    int wr = w >> 1, wc = w & 1;
    int m0 = blockIdx.x * 128 + wr * 64;
    int n0 = blockIdx.y * 128 + wc * 64;
    int ml = l & 15, kg = l >> 4;
    const ushort* aBase = hAll + (size_t)(m0 + ml) * 512 + kg * 8;
    const ushort* bBase = WfcT + (size_t)(n0 + ml) * 512 + kg * 8;
    f32x4 acc[4][4] = {};
#pragma unroll 2
    for (int k0 = 0; k0 < 512; k0 += 32) {
        bf16x8 bfr[4], afr[4];
#pragma unroll
        for (int nf = 0; nf < 4; ++nf)
            bfr[nf] = *(const bf16x8*)(bBase + (size_t)nf * 16 * 512 + k0);
#pragma unroll
        for (int mf = 0; mf < 4; ++mf)
            afr[mf] = *(const bf16x8*)(aBase + (size_t)mf * 16 * 512 + k0);
#pragma unroll
        for (int mf = 0; mf < 4; ++mf)
#pragma unroll
            for (int nf = 0; nf < 4; ++nf)
                acc[mf][nf] = __builtin_amdgcn_mfma_f32_16x16x32_bf16(afr[mf], bfr[nf], acc[mf][nf], 0, 0, 0);
    }
#pragma unroll
    for (int mf = 0; mf < 4; ++mf)
#pragma unroll
        for (int nf = 0; nf < 4; ++nf) {
            int col = n0 + nf * 16 + ml;
            if (col < NVOCAB) {
                float bias = bfc[col];
#pragma unroll
                for (int r = 0; r < 4; ++r) {
                    int row = m0 + mf * 16 + kg * 4 + r;
                    int t = row >> 6, b = row & 63;
                    bool act = t < (lens[b] - 1);
                    pred[((size_t)b * TSTEPS + t) * NVOCAB + col] = act ? acc[mf][nf][r] + bias : 0.f;
                }
            }
        }
}

extern "C" void kernel_launch(void* const* d_in, const int* in_sizes, int n_in,
                              void* d_out, int out_size, void* d_ws, size_t ws_size,
                              hipStream_t stream) {
    const float* enc  = (const float*)d_in[0];
    const int*   caps = (const int*)d_in[1];
    const int*   lens = (const int*)d_in[2];
    const float* emb  = (const float*)d_in[3];
    const float* We   = (const float*)d_in[4];
    const float* be   = (const float*)d_in[5];
    const float* Wd   = (const float*)d_in[6];
    const float* bd   = (const float*)d_in[7];
    const float* vatt = (const float*)d_in[8];
    const float* bv   = (const float*)d_in[9];
    const float* Wih  = (const float*)d_in[10];
    const float* bih  = (const float*)d_in[11];
    const float* Whh  = (const float*)d_in[12];
    const float* bhh  = (const float*)d_in[13];
    const float* Winh = (const float*)d_in[14];
    const float* binh = (const float*)d_in[15];
    const float* Winc = (const float*)d_in[16];
    const float* binc = (const float*)d_in[17];
    const float* Wfb  = (const float*)d_in[18];
    const float* bfb  = (const float*)d_in[19];
    const float* Wfc  = (const float*)d_in[20];
    const float* bfc  = (const float*)d_in[21];

    float* out       = (float*)d_out;
    float* pred_out  = out;
    float* cap_out   = out + 15360000;
    float* len_out   = out + 15361600;
    float* alpha_out = out + 15361664;

    char* p = (char*)d_ws;
    ushort* att1b    = (ushort*)p; p += (size_t)12544 * 512 * 2;
    ushort* WTj      = (ushort*)p; p += (size_t)2048 * KX * 2;
    ushort* WfcT     = (ushort*)p; p += (size_t)NPAD * 512 * 2;
    ushort* BpreT    = (ushort*)p; p += (size_t)2560 * 512 * 2;
    ushort* WeT      = (ushort*)p; p += (size_t)512 * 2048 * 2;
    ushort* embpartb = (ushort*)p; p += (size_t)1536 * 2048 * 2;
    ushort* hAll     = (ushort*)p; p += (size_t)1536 * 512 * 2;
    ushort* ctxb     = (ushort*)p; p += (size_t)64 * 2048 * 2;   // aliased: hcacc
    ushort* hb0      = (ushort*)p; p += (size_t)64 * 512 * 2;
    ushort* hb1      = (ushort*)p; p += (size_t)64 * 512 * 2;
    float* c         = (float*)p;  p += (size_t)64 * 512 * 4;
    ushort* meanb    = (ushort*)p; p += (size_t)64 * 2048 * 2;
    ushort* encb     = (ushort*)p; p += (size_t)64 * NPIX * ENCD * 2;
    float* hcacc     = (float*)ctxb;

    // weight prep
    k_cp_wtj<<<2048, 256, 0, stream>>>(Wih, Whh, caps, lens, WTj, cap_out, len_out);
    k_tr_bpre<<<dim3(80, 16), 256, 0, stream>>>(Wd, Wfb, BpreT);
    k_tr_wfct<<<dim3(316, 16), 256, 0, stream>>>(Wfc, WfcT);
    k_tr_wet<<<dim3(16, 64), 256, 0, stream>>>(We, WeT);
    k_embpart<<<dim3(24, 32), 256, 0, stream>>>(caps, emb, WTj, embpartb);
    hipMemsetAsync(hcacc, 0, (size_t)64 * 1024 * 4, stream);
    // enc conversion + init
    k_encconv<<<12544, 256, 0, stream>>>(enc, encb);
    k_meanb<<<dim3(64, 2), 256, 0, stream>>>(encb, meanb);
    k_initp<<<dim3(16, 4, 8), 256, 0, stream>>>(meanb, Winh, Winc, hcacc);
    k_initfin<<<32, 256, 0, stream>>>(hcacc, binh, binc, hb0, c);
    k_att1<<<dim3(98, 4), 256, 0, stream>>>(encb, WeT, be, att1b);

    KP kp;
    kp.encb = encb; kp.att1b = att1b; kp.WTj = WTj; kp.BpreT = BpreT;
    kp.embpartb = embpartb; kp.vatt = vatt; kp.bv = bv; kp.bd = bd;
    kp.bfb = bfb; kp.bih = bih; kp.bhh = bhh; kp.lens = lens;
    kp.ctxb = ctxb; kp.hb0 = hb0; kp.hb1 = hb1; kp.c = c;
    kp.hAll = hAll; kp.alpha_out = alpha_out;
    void* args[] = { &kp };
    hipLaunchCooperativeKernel((void*)k_loop, dim3(256), dim3(512), args, 0, stream);

    k_predall<<<dim3(12, 79), 256, 0, stream>>>(hAll, WfcT, bfc, lens, pred_out);
}